// Round 1
// baseline (1173.386 us; speedup 1.0000x reference)
//
#include <hip/hip_runtime.h>
#include <hip/hip_bf16.h>

#define NN 100000
#define NE 800000
#define INC 64
#define HID 128
#define KC 9

// glob layout (floats): x_pool[1152] | out_adj[81] | ss[81] | den[1]  => 1315
#define G_XP 0
#define G_OA 1152
#define G_SS 1233
#define G_DEN 1314

__device__ __forceinline__ float atomAddG(float* p, float v) {
  // HW global_atomic_add_f32 (no CAS loop); values are never denormal-critical here
  return unsafeAtomicAdd(p, v);
}

__global__ __launch_bounds__(256) void k_count(const int* __restrict__ dst, float* __restrict__ deg) {
  int i = blockIdx.x * blockDim.x + threadIdx.x;
  int stride = gridDim.x * blockDim.x;
  for (; i < NE; i += stride) atomAddG(&deg[dst[i]], 1.0f);
}

__global__ __launch_bounds__(256) void k_dinv(const float* __restrict__ deg, float* __restrict__ dinv) {
  int i = blockIdx.x * blockDim.x + threadIdx.x;
  if (i < NN) dinv[i] = rsqrtf(deg[i] + 1.0f);  // deg includes +1 self loop => >= 1
}

__global__ __launch_bounds__(256) void k_scatter(const int* __restrict__ src, const int* __restrict__ dst,
                                                 const float* __restrict__ dinv, const float* __restrict__ x,
                                                 float* __restrict__ agg) {
  int tid = blockIdx.x * blockDim.x + threadIdx.x;
  int lane16 = tid & 15;
  int e = tid >> 4;
  int estride = (gridDim.x * blockDim.x) >> 4;
  for (; e < NE; e += estride) {
    int r = src[e], c = dst[e];
    float w = dinv[r] * dinv[c];
    float4 xv = ((const float4*)(x + (size_t)r * INC))[lane16];
    float* ap = agg + (size_t)c * INC + lane16 * 4;
    atomAddG(ap + 0, w * xv.x);
    atomAddG(ap + 1, w * xv.y);
    atomAddG(ap + 2, w * xv.z);
    atomAddG(ap + 3, w * xv.w);
  }
}

__global__ __launch_bounds__(256) void k_node(const float* __restrict__ agg, const float* __restrict__ x,
                                              const float* __restrict__ dinv, const float* __restrict__ deg,
                                              const float* __restrict__ W1, const float* __restrict__ b1,
                                              const float* __restrict__ Wp, const float* __restrict__ bp,
                                              float* __restrict__ s_out, float* __restrict__ glob) {
  __shared__ float W1s[INC * HID];   // 32 KB
  __shared__ float Wps[HID * KC];    // 4.6 KB
  __shared__ float b1s[HID];
  __shared__ float bps[KC];
  __shared__ float a_sh[4][INC];     // wave-private rows
  __shared__ float pool_sh[KC * HID];
  __shared__ float ss_sh[KC * KC];
  __shared__ float den_sh;

  int t = threadIdx.x;
  for (int i = t; i < (INC * HID) / 4; i += 256) ((float4*)W1s)[i] = ((const float4*)W1)[i];
  for (int i = t; i < HID * KC; i += 256) Wps[i] = Wp[i];
  if (t < HID) b1s[t] = b1[t];
  if (t < KC) bps[t] = bp[t];
  for (int i = t; i < KC * HID; i += 256) pool_sh[i] = 0.f;
  if (t < KC * KC) ss_sh[t] = 0.f;
  if (t == 0) den_sh = 0.f;
  __syncthreads();

  int wave = t >> 6, lane = t & 63;
  int gw = blockIdx.x * 4 + wave;
  int nw = gridDim.x * 4;
  float* aw = a_sh[wave];
  const int c0 = 2 * lane, c1 = 2 * lane + 1;

  float pool0[KC], pool1[KC], ssr[KC];
  float den_acc = 0.f;
#pragma unroll
  for (int q = 0; q < KC; ++q) { pool0[q] = 0.f; pool1[q] = 0.f; ssr[q] = 0.f; }

  for (int node = gw; node < NN; node += nw) {
    float dv = dinv[node];
    float al = agg[(size_t)node * INC + lane] + dv * dv * x[(size_t)node * INC + lane];
    aw[lane] = al;  // wave-private LDS: same-wave ordering, no barrier needed

    float h0 = b1s[c0], h1 = b1s[c1];
#pragma unroll
    for (int k = 0; k < INC; ++k) {
      float a = aw[k];
      h0 = fmaf(a, W1s[k * HID + c0], h0);
      h1 = fmaf(a, W1s[k * HID + c1], h1);
    }
    h0 = fmaxf(h0, 0.f);
    h1 = fmaxf(h1, 0.f);

    float p[KC];
#pragma unroll
    for (int q = 0; q < KC; ++q)
      p[q] = fmaf(h0, Wps[c0 * KC + q], h1 * Wps[c1 * KC + q]);
#pragma unroll
    for (int off = 32; off > 0; off >>= 1) {
#pragma unroll
      for (int q = 0; q < KC; ++q) p[q] += __shfl_xor(p[q], off, 64);
    }
#pragma unroll
    for (int q = 0; q < KC; ++q) p[q] += bps[q];

    float m = p[0];
#pragma unroll
    for (int q = 1; q < KC; ++q) m = fmaxf(m, p[q]);
    float Z = 0.f;
#pragma unroll
    for (int q = 0; q < KC; ++q) { p[q] = __expf(p[q] - m); Z += p[q]; }
    float inv = 1.0f / Z;
#pragma unroll
    for (int q = 0; q < KC; ++q) p[q] *= inv;  // p = s[node]

    float sq = p[0];
#pragma unroll
    for (int q = 1; q < KC; ++q) sq = (lane == q) ? p[q] : sq;

    if (lane < KC) {
      s_out[(size_t)node * KC + lane] = sq;
#pragma unroll
      for (int q = 0; q < KC; ++q) ssr[q] = fmaf(sq, p[q], ssr[q]);
      den_acc = fmaf(deg[node] * sq, sq, den_acc);
    }
#pragma unroll
    for (int q = 0; q < KC; ++q) {
      pool0[q] = fmaf(p[q], h0, pool0[q]);
      pool1[q] = fmaf(p[q], h1, pool1[q]);
    }
  }

#pragma unroll
  for (int q = 0; q < KC; ++q) {
    atomicAdd(&pool_sh[q * HID + c0], pool0[q]);
    atomicAdd(&pool_sh[q * HID + c1], pool1[q]);
  }
  if (lane < KC) {
#pragma unroll
    for (int q = 0; q < KC; ++q) atomicAdd(&ss_sh[lane * KC + q], ssr[q]);
    atomicAdd(&den_sh, den_acc);
  }
  __syncthreads();

  for (int i = t; i < KC * HID; i += 256) atomAddG(&glob[G_XP + i], pool_sh[i]);
  if (t < KC * KC) atomAddG(&glob[G_SS + t], ss_sh[t]);
  if (t == 0) atomAddG(&glob[G_DEN], den_sh);
}

__global__ __launch_bounds__(256) void k_outadj(const int* __restrict__ src, const int* __restrict__ dst,
                                                const float* __restrict__ s, float* __restrict__ oa_g) {
  __shared__ float oash[81];
  int t = threadIdx.x;
  if (t < 81) oash[t] = 0.f;
  __syncthreads();

  float acc[81];
#pragma unroll
  for (int i = 0; i < 81; ++i) acc[i] = 0.f;

  int stride = gridDim.x * blockDim.x;
  for (int e = blockIdx.x * blockDim.x + t; e < NE; e += stride) {
    const float* sa = s + (size_t)src[e] * KC;
    const float* sb = s + (size_t)dst[e] * KC;
    float a[9], b[9];
#pragma unroll
    for (int i = 0; i < 9; ++i) { a[i] = sa[i]; b[i] = sb[i]; }
#pragma unroll
    for (int i = 0; i < 9; ++i)
#pragma unroll
      for (int j = 0; j < 9; ++j) acc[i * 9 + j] = fmaf(a[i], b[j], acc[i * 9 + j]);
  }

#pragma unroll
  for (int i = 0; i < 81; ++i) atomicAdd(&oash[i], acc[i]);
  __syncthreads();
  if (t < 81) atomAddG(&oa_g[t], oash[t]);
}

__global__ __launch_bounds__(128) void k_final(const float* __restrict__ glob, float* __restrict__ out) {
  const float* xp = glob + G_XP;
  const float* oa = glob + G_OA;
  const float* ssm = glob + G_SS;
  const float* den = glob + G_DEN;
  int t = threadIdx.x;
  __shared__ float red[128];

  // out[0..1151] = log_softmax(x_pool, axis=-1)
  for (int k = 0; k < 9; ++k) {
    float v = xp[k * 128 + t];
    red[t] = v;
    __syncthreads();
    for (int s2 = 64; s2 > 0; s2 >>= 1) {
      if (t < s2) red[t] = fmaxf(red[t], red[t + s2]);
      __syncthreads();
    }
    float m = red[0];
    __syncthreads();
    red[t] = expf(v - m);
    __syncthreads();
    for (int s2 = 64; s2 > 0; s2 >>= 1) {
      if (t < s2) red[t] += red[t + s2];
      __syncthreads();
    }
    float lz = logf(red[0]) + m;
    __syncthreads();
    out[k * 128 + t] = v - lz;
  }

  if (t == 0) {
    float num = 0.f;
    for (int q = 0; q < 9; ++q) num += oa[q * 9 + q];
    out[1152] = -(num / (den[0] + 1e-15f));

    float fn = 0.f;
    for (int i = 0; i < 81; ++i) fn += ssm[i] * ssm[i];
    float rfn = 1.0f / sqrtf(fn);
    float osum = 0.f;
    for (int i = 0; i < 9; ++i)
      for (int j = 0; j < 9; ++j) {
        float v = ssm[i * 9 + j] * rfn - ((i == j) ? (1.0f / 3.0f) : 0.f);
        osum += v * v;
      }
    out[1153] = sqrtf(osum);
  }

  __shared__ float dsh[9];
  if (t < 9) {
    float d = 0.f;
    for (int j = 0; j < 9; ++j)
      if (j != t) d += oa[t * 9 + j];
    dsh[t] = 1.0f / sqrtf(d + 1e-15f);
  }
  __syncthreads();
  if (t < 81) {
    int i = t / 9, j = t % 9;
    out[901154 + t] = (i == j) ? 0.f : dsh[i] * oa[t] * dsh[j];
  }
}

extern "C" void kernel_launch(void* const* d_in, const int* in_sizes, int n_in,
                              void* d_out, int out_size, void* d_ws, size_t ws_size,
                              hipStream_t stream) {
  const float* x = (const float*)d_in[0];
  const int* ei = (const int*)d_in[1];
  // d_in[2] = batch (unused, single graph)
  const float* W1 = (const float*)d_in[3];
  const float* b1 = (const float*)d_in[4];
  const float* Wp = (const float*)d_in[5];
  const float* bp = (const float*)d_in[6];
  float* out = (float*)d_out;
  float* ws = (float*)d_ws;

  float* deg = ws;                                    // [NN]
  float* dinv = ws + NN;                              // [NN]
  float* agg = ws + 2 * (size_t)NN;                   // [NN*INC]
  float* glob = ws + 2 * (size_t)NN + (size_t)NN * INC;  // [1315]

  size_t zero_bytes = (size_t)(2 * NN + NN * INC + 1315) * sizeof(float);
  hipMemsetAsync(d_ws, 0, zero_bytes, stream);

  const int* src = ei;
  const int* dst = ei + NE;

  hipLaunchKernelGGL(k_count, dim3(1024), dim3(256), 0, stream, dst, deg);
  hipLaunchKernelGGL(k_dinv, dim3((NN + 255) / 256), dim3(256), 0, stream, deg, dinv);
  hipLaunchKernelGGL(k_scatter, dim3(2048), dim3(256), 0, stream, src, dst, dinv, x, agg);
  hipLaunchKernelGGL(k_node, dim3(512), dim3(256), 0, stream, agg, x, dinv, deg,
                     W1, b1, Wp, bp, out + 1154, glob);
  hipLaunchKernelGGL(k_outadj, dim3(256), dim3(256), 0, stream, src, dst, out + 1154, glob + G_OA);
  hipLaunchKernelGGL(k_final, dim3(1), dim3(128), 0, stream, glob, out);
}

// Round 2
// 944.192 us; speedup vs baseline: 1.2427x; 1.2427x over previous
//
#include <hip/hip_runtime.h>
#include <hip/hip_bf16.h>

#define NN 100000
#define NE 800000
#define INC 64
#define HID 128
#define KC 9

// glob layout (floats): x_pool[1152] | out_adj[81] | ss[81] | den[1]  => 1315
#define G_XP 0
#define G_OA 1152
#define G_SS 1233
#define G_DEN 1314

__device__ __forceinline__ float atomAddG(float* p, float v) {
  return unsafeAtomicAdd(p, v);  // HW global_atomic_add_f32
}

// ---- CSR build: histogram -> scan -> fill ------------------------------

__global__ __launch_bounds__(256) void k_deg(const int* __restrict__ dst, int* __restrict__ degi) {
  int i = blockIdx.x * blockDim.x + threadIdx.x;
  int stride = gridDim.x * blockDim.x;
  for (; i < NE; i += stride) atomicAdd(&degi[dst[i]], 1);
}

__global__ __launch_bounds__(1024) void k_scan(const int* __restrict__ degi, int* __restrict__ rowptr,
                                               int* __restrict__ cursor, float* __restrict__ dinv) {
  __shared__ int sums[1024];
  int t = threadIdx.x;
  const int CH = (NN + 1023) / 1024;  // 98
  int beg = t * CH;
  int end = min(beg + CH, NN);
  int s = 0;
  for (int i = beg; i < end; ++i) s += degi[i];
  sums[t] = s;
  __syncthreads();
  for (int off = 1; off < 1024; off <<= 1) {
    int v = (t >= off) ? sums[t - off] : 0;
    __syncthreads();
    sums[t] += v;
    __syncthreads();
  }
  int run = (t > 0) ? sums[t - 1] : 0;
  for (int i = beg; i < end; ++i) {
    rowptr[i] = run;
    cursor[i] = run;
    run += degi[i];
    dinv[i] = rsqrtf((float)degi[i] + 1.0f);  // +1 self loop
  }
}

__global__ __launch_bounds__(256) void k_fill(const int* __restrict__ src, const int* __restrict__ dst,
                                              int* __restrict__ cursor, int* __restrict__ csr) {
  int i = blockIdx.x * blockDim.x + threadIdx.x;
  int stride = gridDim.x * blockDim.x;
  for (; i < NE; i += stride) {
    int p = atomicAdd(&cursor[dst[i]], 1);
    csr[p] = src[i];
  }
}

// ---- fused gather (A_hat x) + MLP + softmax + pooled reductions --------

__global__ __launch_bounds__(256) void k_node(const int* __restrict__ rowptr, const int* __restrict__ degi,
                                              const int* __restrict__ csr, const float* __restrict__ x,
                                              const float* __restrict__ dinv,
                                              const float* __restrict__ W1, const float* __restrict__ b1,
                                              const float* __restrict__ Wp, const float* __restrict__ bp,
                                              float* __restrict__ s_out, float* __restrict__ glob) {
  __shared__ float W1s[INC * HID];   // 32 KB
  __shared__ float Wps[HID * KC];
  __shared__ float b1s[HID];
  __shared__ float bps[KC];
  __shared__ float a_sh[4][INC];     // wave-private rows
  __shared__ float pool_sh[KC * HID];
  __shared__ float ss_sh[KC * KC];
  __shared__ float den_sh;

  int t = threadIdx.x;
  for (int i = t; i < (INC * HID) / 4; i += 256) ((float4*)W1s)[i] = ((const float4*)W1)[i];
  for (int i = t; i < HID * KC; i += 256) Wps[i] = Wp[i];
  if (t < HID) b1s[t] = b1[t];
  if (t < KC) bps[t] = bp[t];
  for (int i = t; i < KC * HID; i += 256) pool_sh[i] = 0.f;
  if (t < KC * KC) ss_sh[t] = 0.f;
  if (t == 0) den_sh = 0.f;
  __syncthreads();

  int wave = t >> 6, lane = t & 63;
  int gw = blockIdx.x * 4 + wave;
  int nw = gridDim.x * 4;
  float* aw = a_sh[wave];
  const int c0 = 2 * lane, c1 = 2 * lane + 1;

  float pool0[KC], pool1[KC], ssr[KC];
  float den_acc = 0.f;
#pragma unroll
  for (int q = 0; q < KC; ++q) { pool0[q] = 0.f; pool1[q] = 0.f; ssr[q] = 0.f; }

  for (int node = gw; node < NN; node += nw) {
    float dv = dinv[node];
    int base = rowptr[node];
    int cnt = degi[node];
    float accv = dv * dv * x[(size_t)node * INC + lane];  // self loop
    for (int j0 = 0; j0 < cnt; j0 += 64) {
      int nj = min(64, cnt - j0);
      int sidx = 0;
      float wj = 0.f;
      if (lane < nj) {
        sidx = csr[base + j0 + lane];
        wj = dinv[sidx] * dv;
      }
      for (int j = 0; j < nj; ++j) {
        int si = __shfl(sidx, j, 64);
        float w = __shfl(wj, j, 64);
        accv = fmaf(w, x[(size_t)si * INC + lane], accv);
      }
    }
    aw[lane] = accv;  // wave-private LDS row; same-wave ordering, no barrier

    float h0 = b1s[c0], h1 = b1s[c1];
#pragma unroll
    for (int k = 0; k < INC; ++k) {
      float a = aw[k];
      float2 wv = *(const float2*)&W1s[k * HID + c0];
      h0 = fmaf(a, wv.x, h0);
      h1 = fmaf(a, wv.y, h1);
    }
    h0 = fmaxf(h0, 0.f);
    h1 = fmaxf(h1, 0.f);

    float p[KC];
#pragma unroll
    for (int q = 0; q < KC; ++q)
      p[q] = fmaf(h0, Wps[c0 * KC + q], h1 * Wps[c1 * KC + q]);
#pragma unroll
    for (int off = 32; off > 0; off >>= 1) {
#pragma unroll
      for (int q = 0; q < KC; ++q) p[q] += __shfl_xor(p[q], off, 64);
    }
#pragma unroll
    for (int q = 0; q < KC; ++q) p[q] += bps[q];

    float m = p[0];
#pragma unroll
    for (int q = 1; q < KC; ++q) m = fmaxf(m, p[q]);
    float Z = 0.f;
#pragma unroll
    for (int q = 0; q < KC; ++q) { p[q] = __expf(p[q] - m); Z += p[q]; }
    float inv = 1.0f / Z;
#pragma unroll
    for (int q = 0; q < KC; ++q) p[q] *= inv;  // p = s[node]

    float sq = p[0];
#pragma unroll
    for (int q = 1; q < KC; ++q) sq = (lane == q) ? p[q] : sq;

    if (lane < KC) {
      s_out[(size_t)node * KC + lane] = sq;
#pragma unroll
      for (int q = 0; q < KC; ++q) ssr[q] = fmaf(sq, p[q], ssr[q]);
      den_acc = fmaf((float)cnt * sq, sq, den_acc);
    }
#pragma unroll
    for (int q = 0; q < KC; ++q) {
      pool0[q] = fmaf(p[q], h0, pool0[q]);
      pool1[q] = fmaf(p[q], h1, pool1[q]);
    }
  }

#pragma unroll
  for (int q = 0; q < KC; ++q) {
    atomicAdd(&pool_sh[q * HID + c0], pool0[q]);
    atomicAdd(&pool_sh[q * HID + c1], pool1[q]);
  }
  if (lane < KC) {
#pragma unroll
    for (int q = 0; q < KC; ++q) atomicAdd(&ss_sh[lane * KC + q], ssr[q]);
    atomicAdd(&den_sh, den_acc);
  }
  __syncthreads();

  for (int i = t; i < KC * HID; i += 256) atomAddG(&glob[G_XP + i], pool_sh[i]);
  if (t < KC * KC) atomAddG(&glob[G_SS + t], ss_sh[t]);
  if (t == 0) atomAddG(&glob[G_DEN], den_sh);
}

// ---- out_adj = sum_e s[src] (x) s[dst] ---------------------------------

__global__ __launch_bounds__(256) void k_outadj(const int* __restrict__ src, const int* __restrict__ dst,
                                                const float* __restrict__ s, float* __restrict__ oa_g) {
  __shared__ float oash[81];
  int t = threadIdx.x;
  if (t < 81) oash[t] = 0.f;
  __syncthreads();

  float acc[81];
#pragma unroll
  for (int i = 0; i < 81; ++i) acc[i] = 0.f;

  int stride = gridDim.x * blockDim.x;
  for (int e = blockIdx.x * blockDim.x + t; e < NE; e += stride) {
    const float* sa = s + (size_t)src[e] * KC;
    const float* sb = s + (size_t)dst[e] * KC;
    float a[9], b[9];
#pragma unroll
    for (int i = 0; i < 9; ++i) { a[i] = sa[i]; b[i] = sb[i]; }
#pragma unroll
    for (int i = 0; i < 9; ++i)
#pragma unroll
      for (int j = 0; j < 9; ++j) acc[i * 9 + j] = fmaf(a[i], b[j], acc[i * 9 + j]);
  }

#pragma unroll
  for (int i = 0; i < 81; ++i) atomicAdd(&oash[i], acc[i]);
  __syncthreads();
  if (t < 81) atomAddG(&oa_g[t], oash[t]);
}

// ---- epilogue ----------------------------------------------------------

__global__ __launch_bounds__(128) void k_final(const float* __restrict__ glob, float* __restrict__ out) {
  const float* xp = glob + G_XP;
  const float* oa = glob + G_OA;
  const float* ssm = glob + G_SS;
  const float* den = glob + G_DEN;
  int t = threadIdx.x;
  __shared__ float red[128];

  for (int k = 0; k < 9; ++k) {
    float v = xp[k * 128 + t];
    red[t] = v;
    __syncthreads();
    for (int s2 = 64; s2 > 0; s2 >>= 1) {
      if (t < s2) red[t] = fmaxf(red[t], red[t + s2]);
      __syncthreads();
    }
    float m = red[0];
    __syncthreads();
    red[t] = expf(v - m);
    __syncthreads();
    for (int s2 = 64; s2 > 0; s2 >>= 1) {
      if (t < s2) red[t] += red[t + s2];
      __syncthreads();
    }
    float lz = logf(red[0]) + m;
    __syncthreads();
    out[k * 128 + t] = v - lz;
  }

  if (t == 0) {
    float num = 0.f;
    for (int q = 0; q < 9; ++q) num += oa[q * 9 + q];
    out[1152] = -(num / (den[0] + 1e-15f));

    float fn = 0.f;
    for (int i = 0; i < 81; ++i) fn += ssm[i] * ssm[i];
    float rfn = 1.0f / sqrtf(fn);
    float osum = 0.f;
    for (int i = 0; i < 9; ++i)
      for (int j = 0; j < 9; ++j) {
        float v = ssm[i * 9 + j] * rfn - ((i == j) ? (1.0f / 3.0f) : 0.f);
        osum += v * v;
      }
    out[1153] = sqrtf(osum);
  }

  __shared__ float dsh[9];
  if (t < 9) {
    float d = 0.f;
    for (int j = 0; j < 9; ++j)
      if (j != t) d += oa[t * 9 + j];
    dsh[t] = 1.0f / sqrtf(d + 1e-15f);
  }
  __syncthreads();
  if (t < 81) {
    int i = t / 9, j = t % 9;
    out[901154 + t] = (i == j) ? 0.f : dsh[i] * oa[t] * dsh[j];
  }
}

extern "C" void kernel_launch(void* const* d_in, const int* in_sizes, int n_in,
                              void* d_out, int out_size, void* d_ws, size_t ws_size,
                              hipStream_t stream) {
  const float* x = (const float*)d_in[0];
  const int* ei = (const int*)d_in[1];
  const float* W1 = (const float*)d_in[3];
  const float* b1 = (const float*)d_in[4];
  const float* Wp = (const float*)d_in[5];
  const float* bp = (const float*)d_in[6];
  float* out = (float*)d_out;

  // ws layout: deg_i[NN] | glob[1315] | rowptr[NN] | cursor[NN] | csr[NE] | dinv[NN]
  int* deg_i = (int*)d_ws;
  float* glob = (float*)d_ws + NN;
  int* rowptr = (int*)d_ws + NN + 1315;
  int* cursor = rowptr + NN;
  int* csr = cursor + NN;
  float* dinv = (float*)(csr + NE);

  hipMemsetAsync(d_ws, 0, (size_t)(NN + 1315) * sizeof(float), stream);

  const int* src = ei;
  const int* dst = ei + NE;

  hipLaunchKernelGGL(k_deg, dim3(1024), dim3(256), 0, stream, dst, deg_i);
  hipLaunchKernelGGL(k_scan, dim3(1), dim3(1024), 0, stream, deg_i, rowptr, cursor, dinv);
  hipLaunchKernelGGL(k_fill, dim3(1024), dim3(256), 0, stream, src, dst, cursor, csr);
  hipLaunchKernelGGL(k_node, dim3(768), dim3(256), 0, stream, rowptr, deg_i, csr, x, dinv,
                     W1, b1, Wp, bp, out + 1154, glob);
  hipLaunchKernelGGL(k_outadj, dim3(256), dim3(256), 0, stream, src, dst, out + 1154, glob + G_OA);
  hipLaunchKernelGGL(k_final, dim3(1), dim3(128), 0, stream, glob, out);
}

// Round 3
// 690.135 us; speedup vs baseline: 1.7002x; 1.3681x over previous
//
#include <hip/hip_runtime.h>
#include <hip/hip_bf16.h>

#define NN 100000
#define NE 800000
#define INC 64
#define HID 128
#define KC 9

// glob layout (floats): x_pool[1152] | out_adj[81] | ss[81] | den[1]  => 1315
#define G_XP 0
#define G_OA 1152
#define G_SS 1233
#define G_DEN 1314

__device__ __forceinline__ float atomAddG(float* p, float v) {
  return unsafeAtomicAdd(p, v);  // HW global_atomic_add_f32
}

// ---- CSR build: histogram -> scan -> fill ------------------------------

__global__ __launch_bounds__(256) void k_deg(const int* __restrict__ dst, int* __restrict__ degi) {
  int i = blockIdx.x * blockDim.x + threadIdx.x;
  int stride = gridDim.x * blockDim.x;
  for (; i < NE; i += stride) atomicAdd(&degi[dst[i]], 1);
}

__global__ __launch_bounds__(1024) void k_scan(const int* __restrict__ degi, int* __restrict__ rowptr,
                                               int* __restrict__ cursor, float* __restrict__ dinv) {
  __shared__ int sums[1024];
  int t = threadIdx.x;
  const int CH = (NN + 1023) / 1024;  // 98
  int beg = t * CH;
  int end = min(beg + CH, NN);
  int s = 0;
  for (int i = beg; i < end; ++i) s += degi[i];
  sums[t] = s;
  __syncthreads();
  for (int off = 1; off < 1024; off <<= 1) {
    int v = (t >= off) ? sums[t - off] : 0;
    __syncthreads();
    sums[t] += v;
    __syncthreads();
  }
  int run = (t > 0) ? sums[t - 1] : 0;
  for (int i = beg; i < end; ++i) {
    rowptr[i] = run;
    cursor[i] = run;
    run += degi[i];
    dinv[i] = rsqrtf((float)degi[i] + 1.0f);  // +1 self loop
  }
}

__global__ __launch_bounds__(256) void k_fill(const int* __restrict__ src, const int* __restrict__ dst,
                                              int* __restrict__ cursor, int* __restrict__ csr) {
  int i = blockIdx.x * blockDim.x + threadIdx.x;
  int stride = gridDim.x * blockDim.x;
  for (; i < NE; i += stride) {
    int p = atomicAdd(&cursor[dst[i]], 1);
    csr[p] = src[i];
  }
}

// ---- fused gather (A_hat x) + MLP + softmax + pooled reductions --------
// LDS kept under 40 KB (pool/ss/den alias W1s after the node loop) => 4 blocks/CU.

__global__ __launch_bounds__(256) void k_node(const int* __restrict__ rowptr, const int* __restrict__ degi,
                                              const int* __restrict__ csr, const float* __restrict__ x,
                                              const float* __restrict__ dinv,
                                              const float* __restrict__ W1, const float* __restrict__ b1,
                                              const float* __restrict__ Wp, const float* __restrict__ bp,
                                              float* __restrict__ s_out, float* __restrict__ s_pad,
                                              float* __restrict__ glob) {
  __shared__ float W1s[INC * HID];   // 32 KB; reused for pool/ss/den at epilogue
  __shared__ float Wps[HID * KC];    // 4.5 KB
  __shared__ float b1s[HID];
  __shared__ float bps[KC];
  __shared__ float a_sh[4][INC];     // wave-private rows

  int t = threadIdx.x;
  for (int i = t; i < (INC * HID) / 4; i += 256) ((float4*)W1s)[i] = ((const float4*)W1)[i];
  for (int i = t; i < HID * KC; i += 256) Wps[i] = Wp[i];
  if (t < HID) b1s[t] = b1[t];
  if (t < KC) bps[t] = bp[t];
  __syncthreads();

  int wave = t >> 6, lane = t & 63;
  int gw = blockIdx.x * 4 + wave;
  int nw = gridDim.x * 4;
  float* aw = a_sh[wave];
  const int c0 = 2 * lane, c1 = 2 * lane + 1;
  const int eg = lane >> 4;   // edge subgroup 0..3
  const int c4 = lane & 15;   // channel quad (float4)

  float pool0[KC], pool1[KC], ssr[KC];
  float den_acc = 0.f;
#pragma unroll
  for (int q = 0; q < KC; ++q) { pool0[q] = 0.f; pool1[q] = 0.f; ssr[q] = 0.f; }

  for (int node = gw; node < NN; node += nw) {
    float dv = dinv[node];
    int base = rowptr[node];
    int cnt = degi[node];

    // gather: 4 edges in flight (one per lane subgroup), float4 per lane
    float4 acc = make_float4(0.f, 0.f, 0.f, 0.f);
    for (int j = eg; j < cnt; j += 4) {
      int si = csr[base + j];
      float w = dinv[si] * dv;
      float4 xv = ((const float4*)(x + (size_t)si * INC))[c4];
      acc.x = fmaf(w, xv.x, acc.x);
      acc.y = fmaf(w, xv.y, acc.y);
      acc.z = fmaf(w, xv.z, acc.z);
      acc.w = fmaf(w, xv.w, acc.w);
    }
    // combine the 4 subgroups (channel quad is the same within xor-16/32 pairs)
    acc.x += __shfl_xor(acc.x, 16, 64); acc.y += __shfl_xor(acc.y, 16, 64);
    acc.z += __shfl_xor(acc.z, 16, 64); acc.w += __shfl_xor(acc.w, 16, 64);
    acc.x += __shfl_xor(acc.x, 32, 64); acc.y += __shfl_xor(acc.y, 32, 64);
    acc.z += __shfl_xor(acc.z, 32, 64); acc.w += __shfl_xor(acc.w, 32, 64);
    // self loop
    float dv2 = dv * dv;
    float4 xs = ((const float4*)(x + (size_t)node * INC))[c4];
    acc.x = fmaf(dv2, xs.x, acc.x);
    acc.y = fmaf(dv2, xs.y, acc.y);
    acc.z = fmaf(dv2, xs.z, acc.z);
    acc.w = fmaf(dv2, xs.w, acc.w);
    if (eg == 0) ((float4*)aw)[c4] = acc;  // wave-private LDS; same-wave order

    float h0 = b1s[c0], h1 = b1s[c1];
#pragma unroll
    for (int k = 0; k < INC; ++k) {
      float a = aw[k];
      float2 wv = *(const float2*)&W1s[k * HID + c0];
      h0 = fmaf(a, wv.x, h0);
      h1 = fmaf(a, wv.y, h1);
    }
    h0 = fmaxf(h0, 0.f);
    h1 = fmaxf(h1, 0.f);

    float p[KC];
#pragma unroll
    for (int q = 0; q < KC; ++q)
      p[q] = fmaf(h0, Wps[c0 * KC + q], h1 * Wps[c1 * KC + q]);
#pragma unroll
    for (int off = 32; off > 0; off >>= 1) {
#pragma unroll
      for (int q = 0; q < KC; ++q) p[q] += __shfl_xor(p[q], off, 64);
    }
#pragma unroll
    for (int q = 0; q < KC; ++q) p[q] += bps[q];

    float m = p[0];
#pragma unroll
    for (int q = 1; q < KC; ++q) m = fmaxf(m, p[q]);
    float Z = 0.f;
#pragma unroll
    for (int q = 0; q < KC; ++q) { p[q] = __expf(p[q] - m); Z += p[q]; }
    float inv = 1.0f / Z;
#pragma unroll
    for (int q = 0; q < KC; ++q) p[q] *= inv;  // p = s[node]

    float sq = p[0];
#pragma unroll
    for (int q = 1; q < KC; ++q) sq = (lane == q) ? p[q] : sq;

    if (lane < 12) s_pad[(size_t)node * 12 + lane] = (lane < KC) ? sq : 0.f;
    if (lane < KC) {
      s_out[(size_t)node * KC + lane] = sq;
#pragma unroll
      for (int q = 0; q < KC; ++q) ssr[q] = fmaf(sq, p[q], ssr[q]);
      den_acc = fmaf((float)cnt * sq, sq, den_acc);
    }
#pragma unroll
    for (int q = 0; q < KC; ++q) {
      pool0[q] = fmaf(p[q], h0, pool0[q]);
      pool1[q] = fmaf(p[q], h1, pool1[q]);
    }
  }

  // epilogue: alias pool/ss/den into W1s (all waves done with W1s after barrier)
  __syncthreads();
  float* pool_sh = W1s;              // [KC*HID]
  float* ss_sh = W1s + KC * HID;     // [81]
  float* den_sh = W1s + KC * HID + 81;
  for (int i = t; i < KC * HID + 82; i += 256) W1s[i] = 0.f;
  __syncthreads();

#pragma unroll
  for (int q = 0; q < KC; ++q) {
    atomicAdd(&pool_sh[q * HID + c0], pool0[q]);
    atomicAdd(&pool_sh[q * HID + c1], pool1[q]);
  }
  if (lane < KC) {
#pragma unroll
    for (int q = 0; q < KC; ++q) atomicAdd(&ss_sh[lane * KC + q], ssr[q]);
    atomicAdd(den_sh, den_acc);
  }
  __syncthreads();

  for (int i = t; i < KC * HID; i += 256) atomAddG(&glob[G_XP + i], pool_sh[i]);
  if (t < KC * KC) atomAddG(&glob[G_SS + t], ss_sh[t]);
  if (t == 0) atomAddG(&glob[G_DEN], *den_sh);
}

// ---- out_adj via CSR: g[dst] = sum_{src in N(dst)} s[src]; OA = sum g(x)s[dst]

__global__ __launch_bounds__(256) void k_adj(const int* __restrict__ rowptr, const int* __restrict__ degi,
                                             const int* __restrict__ csr, const float* __restrict__ s_pad,
                                             float* __restrict__ oa_g) {
  int t = threadIdx.x;
  int tid = blockIdx.x * blockDim.x + t;
  int stride = gridDim.x * blockDim.x;

  float acc[81];
#pragma unroll
  for (int i = 0; i < 81; ++i) acc[i] = 0.f;

  for (int node = tid; node < NN; node += stride) {
    int base = rowptr[node];
    int cnt = degi[node];
    float4 g0 = make_float4(0.f, 0.f, 0.f, 0.f);
    float4 g1 = g0;
    float g8 = 0.f;
    for (int j = 0; j < cnt; ++j) {
      int si = csr[base + j];
      const float4* sp = (const float4*)(s_pad + (size_t)si * 12);
      float4 a = sp[0], b = sp[1], c = sp[2];
      g0.x += a.x; g0.y += a.y; g0.z += a.z; g0.w += a.w;
      g1.x += b.x; g1.y += b.y; g1.z += b.z; g1.w += b.w;
      g8 += c.x;
    }
    const float4* sn = (const float4*)(s_pad + (size_t)node * 12);
    float4 d0 = sn[0], d1 = sn[1], d2 = sn[2];
    float gg[9] = {g0.x, g0.y, g0.z, g0.w, g1.x, g1.y, g1.z, g1.w, g8};
    float sd[9] = {d0.x, d0.y, d0.z, d0.w, d1.x, d1.y, d1.z, d1.w, d2.x};
#pragma unroll
    for (int i = 0; i < 9; ++i)
#pragma unroll
      for (int j = 0; j < 9; ++j) acc[i * 9 + j] = fmaf(gg[i], sd[j], acc[i * 9 + j]);
  }

  // wave reduce, then block reduce in LDS, then one global atomic per element
  __shared__ float wsum[4][81];
#pragma unroll
  for (int i = 0; i < 81; ++i) {
#pragma unroll
    for (int off = 32; off > 0; off >>= 1) acc[i] += __shfl_xor(acc[i], off, 64);
  }
  int wave = t >> 6, lane = t & 63;
  if (lane == 0) {
#pragma unroll
    for (int i = 0; i < 81; ++i) wsum[wave][i] = acc[i];
  }
  __syncthreads();
  if (t < 81) atomAddG(&oa_g[t], wsum[0][t] + wsum[1][t] + wsum[2][t] + wsum[3][t]);
}

// ---- epilogue ----------------------------------------------------------

__global__ __launch_bounds__(128) void k_final(const float* __restrict__ glob, float* __restrict__ out) {
  const float* xp = glob + G_XP;
  const float* oa = glob + G_OA;
  const float* ssm = glob + G_SS;
  const float* den = glob + G_DEN;
  int t = threadIdx.x;
  __shared__ float red[128];

  for (int k = 0; k < 9; ++k) {
    float v = xp[k * 128 + t];
    red[t] = v;
    __syncthreads();
    for (int s2 = 64; s2 > 0; s2 >>= 1) {
      if (t < s2) red[t] = fmaxf(red[t], red[t + s2]);
      __syncthreads();
    }
    float m = red[0];
    __syncthreads();
    red[t] = expf(v - m);
    __syncthreads();
    for (int s2 = 64; s2 > 0; s2 >>= 1) {
      if (t < s2) red[t] += red[t + s2];
      __syncthreads();
    }
    float lz = logf(red[0]) + m;
    __syncthreads();
    out[k * 128 + t] = v - lz;
  }

  if (t == 0) {
    float num = 0.f;
    for (int q = 0; q < 9; ++q) num += oa[q * 9 + q];
    out[1152] = -(num / (den[0] + 1e-15f));

    float fn = 0.f;
    for (int i = 0; i < 81; ++i) fn += ssm[i] * ssm[i];
    float rfn = 1.0f / sqrtf(fn);
    float osum = 0.f;
    for (int i = 0; i < 9; ++i)
      for (int j = 0; j < 9; ++j) {
        float v = ssm[i * 9 + j] * rfn - ((i == j) ? (1.0f / 3.0f) : 0.f);
        osum += v * v;
      }
    out[1153] = sqrtf(osum);
  }

  __shared__ float dsh[9];
  if (t < 9) {
    float d = 0.f;
    for (int j = 0; j < 9; ++j)
      if (j != t) d += oa[t * 9 + j];
    dsh[t] = 1.0f / sqrtf(d + 1e-15f);
  }
  __syncthreads();
  if (t < 81) {
    int i = t / 9, j = t % 9;
    out[901154 + t] = (i == j) ? 0.f : dsh[i] * oa[t] * dsh[j];
  }
}

extern "C" void kernel_launch(void* const* d_in, const int* in_sizes, int n_in,
                              void* d_out, int out_size, void* d_ws, size_t ws_size,
                              hipStream_t stream) {
  const float* x = (const float*)d_in[0];
  const int* ei = (const int*)d_in[1];
  const float* W1 = (const float*)d_in[3];
  const float* b1 = (const float*)d_in[4];
  const float* Wp = (const float*)d_in[5];
  const float* bp = (const float*)d_in[6];
  float* out = (float*)d_out;

  // ws layout: deg_i[NN] | glob[1315] | rowptr[NN] | cursor[NN] | csr[NE] | dinv[NN] | s_pad[NN*12]
  int* deg_i = (int*)d_ws;
  float* glob = (float*)d_ws + NN;
  int* rowptr = (int*)d_ws + NN + 1315;
  int* cursor = rowptr + NN;
  int* csr = cursor + NN;
  float* dinv = (float*)(csr + NE);
  float* s_pad = dinv + NN;

  hipMemsetAsync(d_ws, 0, (size_t)(NN + 1315) * sizeof(float), stream);

  const int* src = ei;
  const int* dst = ei + NE;

  hipLaunchKernelGGL(k_deg, dim3(1024), dim3(256), 0, stream, dst, deg_i);
  hipLaunchKernelGGL(k_scan, dim3(1), dim3(1024), 0, stream, deg_i, rowptr, cursor, dinv);
  hipLaunchKernelGGL(k_fill, dim3(1024), dim3(256), 0, stream, src, dst, cursor, csr);
  hipLaunchKernelGGL(k_node, dim3(1024), dim3(256), 0, stream, rowptr, deg_i, csr, x, dinv,
                     W1, b1, Wp, bp, out + 1154, s_pad, glob);
  hipLaunchKernelGGL(k_adj, dim3(192), dim3(256), 0, stream, rowptr, deg_i, csr, s_pad, glob + G_OA);
  hipLaunchKernelGGL(k_final, dim3(1), dim3(128), 0, stream, glob, out);
}

// Round 4
// 440.327 us; speedup vs baseline: 2.6648x; 1.5673x over previous
//
#include <hip/hip_runtime.h>
#include <hip/hip_bf16.h>

#define NN 100000
#define NE 800000
#define INC 64
#define HID 128
#define KC 9
#define NB 98  // ceil(NN/1024) scan blocks

// glob layout (floats): x_pool[1152] | out_adj[81] | ss[81] | den[1]  => 1315
#define G_XP 0
#define G_OA 1152
#define G_SS 1233
#define G_DEN 1314

__device__ __forceinline__ float atomAddG(float* p, float v) {
  return unsafeAtomicAdd(p, v);  // HW global_atomic_add_f32
}

// ---- CSR build: histogram -> 3-phase scan -> fill ----------------------

__global__ __launch_bounds__(256) void k_deg(const int* __restrict__ dst, int* __restrict__ degi) {
  int i = blockIdx.x * blockDim.x + threadIdx.x;
  int stride = gridDim.x * blockDim.x;
  for (; i < NE; i += stride) atomicAdd(&degi[dst[i]], 1);
}

__global__ __launch_bounds__(256) void k_bsum(const int* __restrict__ degi, int* __restrict__ bsum) {
  int t = threadIdx.x;
  int base = blockIdx.x * 1024 + t * 4;
  int d0 = 0, d1 = 0, d2 = 0, d3 = 0;
  if (base + 3 < NN) {
    int4 v = *(const int4*)(degi + base);
    d0 = v.x; d1 = v.y; d2 = v.z; d3 = v.w;
  } else {
    if (base < NN) d0 = degi[base];
    if (base + 1 < NN) d1 = degi[base + 1];
    if (base + 2 < NN) d2 = degi[base + 2];
  }
  int s = d0 + d1 + d2 + d3;
#pragma unroll
  for (int off = 32; off > 0; off >>= 1) s += __shfl_xor(s, off, 64);
  __shared__ int ws[4];
  if ((t & 63) == 0) ws[t >> 6] = s;
  __syncthreads();
  if (t == 0) bsum[blockIdx.x] = ws[0] + ws[1] + ws[2] + ws[3];
}

__global__ __launch_bounds__(128) void k_scanb(const int* __restrict__ bsum, int* __restrict__ boff) {
  __shared__ int sc[128];
  int t = threadIdx.x;
  int v = (t < NB) ? bsum[t] : 0;
  sc[t] = v;
  __syncthreads();
  for (int off = 1; off < 128; off <<= 1) {
    int u = (t >= off) ? sc[t - off] : 0;
    __syncthreads();
    sc[t] += u;
    __syncthreads();
  }
  if (t < NB) boff[t] = sc[t] - v;  // exclusive
}

__global__ __launch_bounds__(256) void k_write(const int* __restrict__ degi, const int* __restrict__ boff,
                                               int* __restrict__ rowptr, int* __restrict__ cursor,
                                               float* __restrict__ dinv) {
  int t = threadIdx.x;
  int base = blockIdx.x * 1024 + t * 4;
  int d0 = 0, d1 = 0, d2 = 0, d3 = 0;
  bool full = (base + 3 < NN);
  if (full) {
    int4 v = *(const int4*)(degi + base);
    d0 = v.x; d1 = v.y; d2 = v.z; d3 = v.w;
  } else {
    if (base < NN) d0 = degi[base];
    if (base + 1 < NN) d1 = degi[base + 1];
    if (base + 2 < NN) d2 = degi[base + 2];
  }
  int tsum = d0 + d1 + d2 + d3;
  __shared__ int sc[256];
  sc[t] = tsum;
  __syncthreads();
  for (int off = 1; off < 256; off <<= 1) {
    int u = (t >= off) ? sc[t - off] : 0;
    __syncthreads();
    sc[t] += u;
    __syncthreads();
  }
  int ex = sc[t] - tsum + boff[blockIdx.x];
  int r0 = ex, r1 = ex + d0, r2 = r1 + d1, r3 = r2 + d2;
  if (full) {
    int4 rv = make_int4(r0, r1, r2, r3);
    *(int4*)(rowptr + base) = rv;
    *(int4*)(cursor + base) = rv;
    float4 dv = make_float4(rsqrtf((float)d0 + 1.f), rsqrtf((float)d1 + 1.f),
                            rsqrtf((float)d2 + 1.f), rsqrtf((float)d3 + 1.f));
    *(float4*)(dinv + base) = dv;
  } else {
    if (base < NN) { rowptr[base] = r0; cursor[base] = r0; dinv[base] = rsqrtf((float)d0 + 1.f); }
    if (base + 1 < NN) { rowptr[base + 1] = r1; cursor[base + 1] = r1; dinv[base + 1] = rsqrtf((float)d1 + 1.f); }
    if (base + 2 < NN) { rowptr[base + 2] = r2; cursor[base + 2] = r2; dinv[base + 2] = rsqrtf((float)d2 + 1.f); }
  }
}

__global__ __launch_bounds__(256) void k_fill(const int* __restrict__ src, const int* __restrict__ dst,
                                              int* __restrict__ cursor, int* __restrict__ csr) {
  int i = blockIdx.x * blockDim.x + threadIdx.x;
  int stride = gridDim.x * blockDim.x;
  for (; i < NE; i += stride) {
    int p = atomicAdd(&cursor[dst[i]], 1);
    csr[p] = src[i];
  }
}

// ---- fused gather (A_hat x) + MLP + softmax + pooled reductions --------

__global__ __launch_bounds__(256) void k_node(const int* __restrict__ rowptr, const int* __restrict__ degi,
                                              const int* __restrict__ csr, const float* __restrict__ x,
                                              const float* __restrict__ dinv,
                                              const float* __restrict__ W1, const float* __restrict__ b1,
                                              const float* __restrict__ Wp, const float* __restrict__ bp,
                                              float* __restrict__ s_out, float* __restrict__ s_pad,
                                              float* __restrict__ glob) {
  __shared__ float W1s[INC * HID];   // 32 KB; reused for pool/ss/den at epilogue
  __shared__ float Wps[HID * KC];
  __shared__ float b1s[HID];
  __shared__ float bps[KC];
  __shared__ float a_sh[4][INC];

  int t = threadIdx.x;
  for (int i = t; i < (INC * HID) / 4; i += 256) ((float4*)W1s)[i] = ((const float4*)W1)[i];
  for (int i = t; i < HID * KC; i += 256) Wps[i] = Wp[i];
  if (t < HID) b1s[t] = b1[t];
  if (t < KC) bps[t] = bp[t];
  __syncthreads();

  int wave = t >> 6, lane = t & 63;
  int gw = blockIdx.x * 4 + wave;
  int nw = gridDim.x * 4;
  float* aw = a_sh[wave];
  const int c0 = 2 * lane, c1 = 2 * lane + 1;
  const int eg = lane >> 4;   // edge subgroup 0..3
  const int c4 = lane & 15;   // channel quad (float4)

  float pool0[KC], pool1[KC], ssr[KC];
  float den_acc = 0.f;
#pragma unroll
  for (int q = 0; q < KC; ++q) { pool0[q] = 0.f; pool1[q] = 0.f; ssr[q] = 0.f; }

  for (int node = gw; node < NN; node += nw) {
    float dv = dinv[node];
    int base = rowptr[node];
    int cnt = degi[node];

    float4 acc = make_float4(0.f, 0.f, 0.f, 0.f);
    for (int j = eg; j < cnt; j += 4) {
      int si = csr[base + j];
      float w = dinv[si] * dv;
      float4 xv = ((const float4*)(x + (size_t)si * INC))[c4];
      acc.x = fmaf(w, xv.x, acc.x);
      acc.y = fmaf(w, xv.y, acc.y);
      acc.z = fmaf(w, xv.z, acc.z);
      acc.w = fmaf(w, xv.w, acc.w);
    }
    acc.x += __shfl_xor(acc.x, 16, 64); acc.y += __shfl_xor(acc.y, 16, 64);
    acc.z += __shfl_xor(acc.z, 16, 64); acc.w += __shfl_xor(acc.w, 16, 64);
    acc.x += __shfl_xor(acc.x, 32, 64); acc.y += __shfl_xor(acc.y, 32, 64);
    acc.z += __shfl_xor(acc.z, 32, 64); acc.w += __shfl_xor(acc.w, 32, 64);
    float dv2 = dv * dv;
    float4 xs = ((const float4*)(x + (size_t)node * INC))[c4];
    acc.x = fmaf(dv2, xs.x, acc.x);
    acc.y = fmaf(dv2, xs.y, acc.y);
    acc.z = fmaf(dv2, xs.z, acc.z);
    acc.w = fmaf(dv2, xs.w, acc.w);
    if (eg == 0) ((float4*)aw)[c4] = acc;  // wave-private LDS; same-wave order

    float h0 = b1s[c0], h1 = b1s[c1];
#pragma unroll
    for (int k = 0; k < INC; ++k) {
      float a = aw[k];
      float2 wv = *(const float2*)&W1s[k * HID + c0];
      h0 = fmaf(a, wv.x, h0);
      h1 = fmaf(a, wv.y, h1);
    }
    h0 = fmaxf(h0, 0.f);
    h1 = fmaxf(h1, 0.f);

    float p[KC];
#pragma unroll
    for (int q = 0; q < KC; ++q)
      p[q] = fmaf(h0, Wps[c0 * KC + q], h1 * Wps[c1 * KC + q]);
#pragma unroll
    for (int off = 32; off > 0; off >>= 1) {
#pragma unroll
      for (int q = 0; q < KC; ++q) p[q] += __shfl_xor(p[q], off, 64);
    }
#pragma unroll
    for (int q = 0; q < KC; ++q) p[q] += bps[q];

    float m = p[0];
#pragma unroll
    for (int q = 1; q < KC; ++q) m = fmaxf(m, p[q]);
    float Z = 0.f;
#pragma unroll
    for (int q = 0; q < KC; ++q) { p[q] = __expf(p[q] - m); Z += p[q]; }
    float inv = 1.0f / Z;
#pragma unroll
    for (int q = 0; q < KC; ++q) p[q] *= inv;  // p = s[node]

    float sq = p[0];
#pragma unroll
    for (int q = 1; q < KC; ++q) sq = (lane == q) ? p[q] : sq;

    if (lane < 12) s_pad[(size_t)node * 12 + lane] = (lane < KC) ? sq : 0.f;
    if (lane < KC) {
      s_out[(size_t)node * KC + lane] = sq;
#pragma unroll
      for (int q = 0; q < KC; ++q) ssr[q] = fmaf(sq, p[q], ssr[q]);
      den_acc = fmaf((float)cnt * sq, sq, den_acc);
    }
#pragma unroll
    for (int q = 0; q < KC; ++q) {
      pool0[q] = fmaf(p[q], h0, pool0[q]);
      pool1[q] = fmaf(p[q], h1, pool1[q]);
    }
  }

  __syncthreads();
  float* pool_sh = W1s;              // [KC*HID]
  float* ss_sh = W1s + KC * HID;     // [81]
  float* den_sh = W1s + KC * HID + 81;
  for (int i = t; i < KC * HID + 82; i += 256) W1s[i] = 0.f;
  __syncthreads();

#pragma unroll
  for (int q = 0; q < KC; ++q) {
    atomicAdd(&pool_sh[q * HID + c0], pool0[q]);
    atomicAdd(&pool_sh[q * HID + c1], pool1[q]);
  }
  if (lane < KC) {
#pragma unroll
    for (int q = 0; q < KC; ++q) atomicAdd(&ss_sh[lane * KC + q], ssr[q]);
    atomicAdd(den_sh, den_acc);
  }
  __syncthreads();

  for (int i = t; i < KC * HID; i += 256) atomAddG(&glob[G_XP + i], pool_sh[i]);
  if (t < KC * KC) atomAddG(&glob[G_SS + t], ss_sh[t]);
  if (t == 0) atomAddG(&glob[G_DEN], *den_sh);
}

// ---- out_adj via CSR: g[dst] = sum_{src in N(dst)} s[src]; OA = sum g(x)s[dst]

__global__ __launch_bounds__(256) void k_adj(const int* __restrict__ rowptr, const int* __restrict__ degi,
                                             const int* __restrict__ csr, const float* __restrict__ s_pad,
                                             float* __restrict__ oa_g) {
  int t = threadIdx.x;
  int tid = blockIdx.x * blockDim.x + t;
  int stride = gridDim.x * blockDim.x;

  float acc[81];
#pragma unroll
  for (int i = 0; i < 81; ++i) acc[i] = 0.f;

  for (int node = tid; node < NN; node += stride) {
    int base = rowptr[node];
    int cnt = degi[node];
    float4 g0 = make_float4(0.f, 0.f, 0.f, 0.f);
    float4 g1 = g0;
    float g8 = 0.f;
    for (int j = 0; j < cnt; ++j) {
      int si = csr[base + j];
      const float4* sp = (const float4*)(s_pad + (size_t)si * 12);
      float4 a = sp[0], b = sp[1], c = sp[2];
      g0.x += a.x; g0.y += a.y; g0.z += a.z; g0.w += a.w;
      g1.x += b.x; g1.y += b.y; g1.z += b.z; g1.w += b.w;
      g8 += c.x;
    }
    const float4* sn = (const float4*)(s_pad + (size_t)node * 12);
    float4 d0 = sn[0], d1 = sn[1], d2 = sn[2];
    float gg[9] = {g0.x, g0.y, g0.z, g0.w, g1.x, g1.y, g1.z, g1.w, g8};
    float sd[9] = {d0.x, d0.y, d0.z, d0.w, d1.x, d1.y, d1.z, d1.w, d2.x};
#pragma unroll
    for (int i = 0; i < 9; ++i)
#pragma unroll
      for (int j = 0; j < 9; ++j) acc[i * 9 + j] = fmaf(gg[i], sd[j], acc[i * 9 + j]);
  }

  __shared__ float wsum[4][81];
#pragma unroll
  for (int i = 0; i < 81; ++i) {
#pragma unroll
    for (int off = 32; off > 0; off >>= 1) acc[i] += __shfl_xor(acc[i], off, 64);
  }
  int wave = t >> 6, lane = t & 63;
  if (lane == 0) {
#pragma unroll
    for (int i = 0; i < 81; ++i) wsum[wave][i] = acc[i];
  }
  __syncthreads();
  if (t < 81) atomAddG(&oa_g[t], wsum[0][t] + wsum[1][t] + wsum[2][t] + wsum[3][t]);
}

// ---- epilogue ----------------------------------------------------------

__global__ __launch_bounds__(128) void k_final(const float* __restrict__ glob, float* __restrict__ out) {
  const float* xp = glob + G_XP;
  const float* oa = glob + G_OA;
  const float* ssm = glob + G_SS;
  const float* den = glob + G_DEN;
  int t = threadIdx.x;
  __shared__ float red[128];

  for (int k = 0; k < 9; ++k) {
    float v = xp[k * 128 + t];
    red[t] = v;
    __syncthreads();
    for (int s2 = 64; s2 > 0; s2 >>= 1) {
      if (t < s2) red[t] = fmaxf(red[t], red[t + s2]);
      __syncthreads();
    }
    float m = red[0];
    __syncthreads();
    red[t] = expf(v - m);
    __syncthreads();
    for (int s2 = 64; s2 > 0; s2 >>= 1) {
      if (t < s2) red[t] += red[t + s2];
      __syncthreads();
    }
    float lz = logf(red[0]) + m;
    __syncthreads();
    out[k * 128 + t] = v - lz;
  }

  if (t == 0) {
    float num = 0.f;
    for (int q = 0; q < 9; ++q) num += oa[q * 9 + q];
    out[1152] = -(num / (den[0] + 1e-15f));

    float fn = 0.f;
    for (int i = 0; i < 81; ++i) fn += ssm[i] * ssm[i];
    float rfn = 1.0f / sqrtf(fn);
    float osum = 0.f;
    for (int i = 0; i < 9; ++i)
      for (int j = 0; j < 9; ++j) {
        float v = ssm[i * 9 + j] * rfn - ((i == j) ? (1.0f / 3.0f) : 0.f);
        osum += v * v;
      }
    out[1153] = sqrtf(osum);
  }

  __shared__ float dsh[9];
  if (t < 9) {
    float d = 0.f;
    for (int j = 0; j < 9; ++j)
      if (j != t) d += oa[t * 9 + j];
    dsh[t] = 1.0f / sqrtf(d + 1e-15f);
  }
  __syncthreads();
  if (t < 81) {
    int i = t / 9, j = t % 9;
    out[901154 + t] = (i == j) ? 0.f : dsh[i] * oa[t] * dsh[j];
  }
}

extern "C" void kernel_launch(void* const* d_in, const int* in_sizes, int n_in,
                              void* d_out, int out_size, void* d_ws, size_t ws_size,
                              hipStream_t stream) {
  const float* x = (const float*)d_in[0];
  const int* ei = (const int*)d_in[1];
  const float* W1 = (const float*)d_in[3];
  const float* b1 = (const float*)d_in[4];
  const float* Wp = (const float*)d_in[5];
  const float* bp = (const float*)d_in[6];
  float* out = (float*)d_out;

  // ws layout: deg_i[NN] | glob[1315] | rowptr[NN] | cursor[NN] | csr[NE] | dinv[NN] | s_pad[NN*12] | bsum[NB] | boff[NB]
  int* deg_i = (int*)d_ws;
  float* glob = (float*)d_ws + NN;
  int* rowptr = (int*)d_ws + NN + 1315;
  int* cursor = rowptr + NN;
  int* csr = cursor + NN;
  float* dinv = (float*)(csr + NE);
  float* s_pad = dinv + NN;
  int* bsum = (int*)(s_pad + (size_t)NN * 12);
  int* boff = bsum + NB;

  hipMemsetAsync(d_ws, 0, (size_t)(NN + 1315) * sizeof(float), stream);

  const int* src = ei;
  const int* dst = ei + NE;

  hipLaunchKernelGGL(k_deg, dim3(1024), dim3(256), 0, stream, dst, deg_i);
  hipLaunchKernelGGL(k_bsum, dim3(NB), dim3(256), 0, stream, deg_i, bsum);
  hipLaunchKernelGGL(k_scanb, dim3(1), dim3(128), 0, stream, bsum, boff);
  hipLaunchKernelGGL(k_write, dim3(NB), dim3(256), 0, stream, deg_i, boff, rowptr, cursor, dinv);
  hipLaunchKernelGGL(k_fill, dim3(1024), dim3(256), 0, stream, src, dst, cursor, csr);
  hipLaunchKernelGGL(k_node, dim3(1024), dim3(256), 0, stream, rowptr, deg_i, csr, x, dinv,
                     W1, b1, Wp, bp, out + 1154, s_pad, glob);
  hipLaunchKernelGGL(k_adj, dim3(192), dim3(256), 0, stream, rowptr, deg_i, csr, s_pad, glob + G_OA);
  hipLaunchKernelGGL(k_final, dim3(1), dim3(128), 0, stream, glob, out);
}